// Round 2
// baseline (117.055 us; speedup 1.0000x reference)
//
#include <hip/hip_runtime.h>

typedef _Float16 half2_t __attribute__((ext_vector_type(2)));
typedef _Float16 half4_t __attribute__((ext_vector_type(4)));
typedef _Float16 half8_t __attribute__((ext_vector_type(8)));
typedef float floatx4 __attribute__((ext_vector_type(4)));

#define T_SEQ 4096
#define D_HEAD 128

// ---------------- QKV projection (MFMA f16, fp32 accumulate) ----------------
// grid: (B*T/64, 3), block: 256 (4 waves). Block computes 64 rows x 128 outs of one matrix.
// Writes q,k as f16 [B*T][128]; v transposed as f16 [B][128][T].
__global__ __launch_bounds__(256) void proj_kernel(
    const float* __restrict__ x,
    const float* __restrict__ Wq, const float* __restrict__ bq,
    const float* __restrict__ Wk, const float* __restrict__ bk,
    const float* __restrict__ Wv, const float* __restrict__ bv,
    _Float16* __restrict__ qf, _Float16* __restrict__ kf, _Float16* __restrict__ vt)
{
    __shared__ __align__(16) _Float16 Ws[128 * 136];  // W[o][i], +8 pad
    __shared__ __align__(16) _Float16 xs[64 * 136];   // x[t][i], +8 pad

    const int t = threadIdx.x;
    const int mat = blockIdx.y;
    const float* W = (mat == 0) ? Wq : (mat == 1) ? Wk : Wv;
    const float* bias = (mat == 0) ? bq : (mat == 1) ? bk : bv;
    const int r0 = blockIdx.x * 64;

    // stage W -> f16 LDS (convert fp32->f16)
    {
        const int o = t >> 1;
        const int i0 = (t & 1) * 64;
        for (int jj = 0; jj < 8; ++jj) {
            floatx4 w0 = *reinterpret_cast<const floatx4*>(W + o * 128 + i0 + jj * 8);
            floatx4 w1 = *reinterpret_cast<const floatx4*>(W + o * 128 + i0 + jj * 8 + 4);
            half8_t h;
            h[0]=(_Float16)w0[0]; h[1]=(_Float16)w0[1]; h[2]=(_Float16)w0[2]; h[3]=(_Float16)w0[3];
            h[4]=(_Float16)w1[0]; h[5]=(_Float16)w1[1]; h[6]=(_Float16)w1[2]; h[7]=(_Float16)w1[3];
            *reinterpret_cast<half8_t*>(&Ws[o * 136 + i0 + jj * 8]) = h;
        }
    }
    // stage x rows -> f16 LDS
    {
        const int row = t >> 2;
        const int c0 = (t & 3) * 32;
        for (int jj = 0; jj < 4; ++jj) {
            floatx4 w0 = *reinterpret_cast<const floatx4*>(x + (size_t)(r0 + row) * 128 + c0 + jj * 8);
            floatx4 w1 = *reinterpret_cast<const floatx4*>(x + (size_t)(r0 + row) * 128 + c0 + jj * 8 + 4);
            half8_t h;
            h[0]=(_Float16)w0[0]; h[1]=(_Float16)w0[1]; h[2]=(_Float16)w0[2]; h[3]=(_Float16)w0[3];
            h[4]=(_Float16)w1[0]; h[5]=(_Float16)w1[1]; h[6]=(_Float16)w1[2]; h[7]=(_Float16)w1[3];
            *reinterpret_cast<half8_t*>(&xs[row * 136 + c0 + jj * 8]) = h;
        }
    }
    __syncthreads();

    const int w = t >> 6;
    const int lane = t & 63;
    const int lo = lane & 15, hi = lane >> 4;

    // out[t][o] = sum_i x[t][i] * W[o][i]  -- both operands indexed by same k=i,
    // so identical k-enumeration (hi*8+j) on A and B makes the hw k-permutation cancel.
    floatx4 acc[8] = {};
    for (int dc = 0; dc < 4; ++dc) {
        half8_t a8 = *reinterpret_cast<const half8_t*>(&xs[(w * 16 + lo) * 136 + dc * 32 + hi * 8]);
        for (int ot = 0; ot < 8; ++ot) {
            half8_t b8 = *reinterpret_cast<const half8_t*>(&Ws[(ot * 16 + lo) * 136 + dc * 32 + hi * 8]);
            acc[ot] = __builtin_amdgcn_mfma_f32_16x16x32_f16(a8, b8, acc[ot], 0, 0, 0);
        }
    }
    __syncthreads();  // everyone done reading xs/Ws before we reuse them

    float bb[8];
    for (int ot = 0; ot < 8; ++ot) bb[ot] = bias[ot * 16 + lo];

    // C/D layout: lane holds D[row=(l>>4)*4+r][col=l&15] -> row_local = hi*4+r, o = ot*16+lo
    if (mat < 2) {
        _Float16* ol = xs;  // reuse as [64][136]
        for (int ot = 0; ot < 8; ++ot)
            for (int r = 0; r < 4; ++r)
                ol[(w * 16 + hi * 4 + r) * 136 + ot * 16 + lo] = (_Float16)(acc[ot][r] + bb[ot]);
        __syncthreads();
        _Float16* dst = (mat == 0) ? qf : kf;
        for (int i = 0; i < 4; ++i) {
            int c = t + 256 * i;
            int row = c >> 4, p = c & 15;
            half8_t v = *reinterpret_cast<const half8_t*>(&ol[row * 136 + p * 8]);
            *reinterpret_cast<half8_t*>(dst + (size_t)(r0 + row) * 128 + p * 8) = v;
        }
    } else {
        _Float16* vl = Ws;  // reuse as [128][72]  (d-major, 64 t-cols + 8 pad)
        for (int ot = 0; ot < 8; ++ot)
            for (int r = 0; r < 4; ++r)
                vl[(ot * 16 + lo) * 72 + w * 16 + hi * 4 + r] = (_Float16)(acc[ot][r] + bb[ot]);
        __syncthreads();
        const int b = r0 >> 12, tl0 = r0 & 4095;
        for (int i = 0; i < 4; ++i) {
            int c = t + 256 * i;
            int d = c >> 3, p = c & 7;
            half8_t v = *reinterpret_cast<const half8_t*>(&vl[d * 72 + p * 8]);
            *reinterpret_cast<half8_t*>(vt + ((size_t)(b * 128 + d)) * 4096 + tl0 + p * 8) = v;
        }
    }
}

// ---------------- flash attention ----------------
// grid: 256 blocks, 1024 threads = 16 waves: 4 q-subtiles (16 rows) x 4 kv-splits.
// Block owns 64 q rows; per iteration stages 64 kv rows (K swizzled, V transposed);
// wave 'split' consumes kv sub-chunk [split*16, split*16+16).
__global__ __launch_bounds__(1024) void attn_kernel(
    const _Float16* __restrict__ qf, const _Float16* __restrict__ kf,
    const _Float16* __restrict__ vt, float* __restrict__ out)
{
    // K: [64][128] f16 XOR-swizzled (16KB) | Vt: [128][72] f16 (18KB) | red_m/red_l
    __shared__ __align__(16) char smem[36864];
    float* red_m = reinterpret_cast<float*>(smem + 34816);
    float* red_l = reinterpret_cast<float*>(smem + 35840);

    const int tid = threadIdx.x;
    const int w = tid >> 6, lane = tid & 63;
    const int lo = lane & 15, hi = lane >> 4;
    const int qsub = w & 3, split = w >> 2;

    // XCD-aware swizzle: 256 blocks = 8 XCDs x 32 contiguous -> one batch's KV per XCD L2
    const int bx = blockIdx.x;
    const int wg = (bx & 7) * 32 + (bx >> 3);
    const int b = wg >> 6;
    const int q0 = (wg & 63) * 64;

    // Q fragments for this wave's 16 q rows (enumeration hi*8+j, matches K load)
    const _Float16* qrow = qf + ((size_t)b * T_SEQ + q0 + qsub * 16 + lo) * 128;
    half8_t qfrag[4];
    for (int dc = 0; dc < 4; ++dc)
        qfrag[dc] = *reinterpret_cast<const half8_t*>(qrow + dc * 32 + hi * 8);

    floatx4 accO[8] = {};          // O[q=lo][d = dt*16 + hi*4 + r], fp32
    float m_run = -1e30f, l_run = 0.f;
    const float SCL = 0.12751742526f;  // log2(e)/sqrt(128)

    const _Float16* kb = kf + (size_t)b * T_SEQ * 128;
    const _Float16* vb = vt + (size_t)b * 128 * 4096;

    for (int t0 = 0; t0 < T_SEQ; t0 += 64) {
        {   // stage K: 64 rows x 16 chunks of 16B, XOR-swizzle bits [6:4] by row&7
            int row = tid >> 4, p = tid & 15;
            uint4 v = *reinterpret_cast<const uint4*>(kb + (size_t)(t0 + row) * 128 + p * 8);
            int lb = (row * 256 + p * 16) ^ ((row & 7) << 4);
            *reinterpret_cast<uint4*>(smem + lb) = v;
        }
        {   // stage Vt: 128 d-rows x 8 chunks (64 kv cols), row stride 144B
            int d = tid >> 3, p = tid & 7;
            uint4 v = *reinterpret_cast<const uint4*>(vb + (size_t)d * 4096 + t0 + p * 8);
            *reinterpret_cast<uint4*>(smem + 16384 + d * 144 + p * 16) = v;
        }
        __syncthreads();

        const int kvl = split * 16;
        // S^T = mfma(K, Q): lane gets S[q=lo][kv = kvl + hi*4 + r]
        floatx4 sac = {0.f, 0.f, 0.f, 0.f};
        for (int dc = 0; dc < 4; ++dc) {
            int krow = kvl + lo;
            int lb = (krow * 256 + dc * 64 + hi * 16) ^ ((krow & 7) << 4);
            half8_t kf8 = *reinterpret_cast<const half8_t*>(smem + lb);
            sac = __builtin_amdgcn_mfma_f32_16x16x32_f16(kf8, qfrag[dc], sac, 0, 0, 0);
        }

        // online softmax in log2 domain; row stats live on all lanes with same lo
        float e0 = sac[0] * SCL, e1 = sac[1] * SCL, e2 = sac[2] * SCL, e3 = sac[3] * SCL;
        float bm = fmaxf(fmaxf(e0, e1), fmaxf(e2, e3));
        bm = fmaxf(bm, __shfl_xor(bm, 16));
        bm = fmaxf(bm, __shfl_xor(bm, 32));
        float m_new = fmaxf(m_run, bm);
        float p0 = exp2f(e0 - m_new), p1 = exp2f(e1 - m_new);
        float p2 = exp2f(e2 - m_new), p3 = exp2f(e3 - m_new);
        float bs = p0 + p1 + p2 + p3;
        bs += __shfl_xor(bs, 16);
        bs += __shfl_xor(bs, 32);
        float alpha = exp2f(m_run - m_new);
        l_run = l_run * alpha + bs;
        m_run = m_new;

        half4_t pa;  // B-operand of PV: pa[j] = P[q=lo][kvl + hi*4 + j] (canonical 16x16x16 k-map)
        pa[0] = (_Float16)p0; pa[1] = (_Float16)p1; pa[2] = (_Float16)p2; pa[3] = (_Float16)p3;
        for (int i = 0; i < 8; ++i) accO[i] *= alpha;

        // O^T = mfma(A=V^T, B=P^T): A[m=d][k=kv] from Vt_lds, out stays on q=lo
        for (int dt = 0; dt < 8; ++dt) {
            const char* vp = smem + 16384 + (dt * 16 + lo) * 144 + (kvl + hi * 4) * 2;
            half4_t vfr = *reinterpret_cast<const half4_t*>(vp);
            accO[dt] = __builtin_amdgcn_mfma_f32_16x16x16f16(vfr, pa, accO[dt], 0, 0, 0);
        }
        __syncthreads();
    }

    // ---- merge the 4 kv-splits per q-subtile ----
    if (lane < 16) { red_m[w * 16 + lane] = m_run; red_l[w * 16 + lane] = l_run; }
    __syncthreads();

    float M = -1e30f;
    for (int ss = 0; ss < 4; ++ss) M = fmaxf(M, red_m[(qsub + 4 * ss) * 16 + lo]);
    float fac = exp2f(m_run - M);

    float* out_lds = reinterpret_cast<float*>(smem);  // [64][130] fp32 (33280B < 34816B)
    for (int ss = 0; ss < 4; ++ss) {
        if (split == ss) {
            int row = qsub * 16 + lo;
            for (int dt = 0; dt < 8; ++dt)
                for (int r = 0; r < 4; ++r) {
                    int d = dt * 16 + hi * 4 + r;
                    float v = accO[dt][r] * fac;
                    if (ss == 0) out_lds[row * 130 + d] = v;
                    else out_lds[row * 130 + d] += v;
                }
        }
        __syncthreads();
    }

    // final normalize + write (coalesced)
    const int row = tid >> 4;
    const int d0 = (tid & 15) * 8;
    const int qq = row & 15, qs = row >> 4;
    float M2 = -1e30f;
    for (int ss = 0; ss < 4; ++ss) M2 = fmaxf(M2, red_m[(qs + 4 * ss) * 16 + qq]);
    float L = 0.f;
    for (int ss = 0; ss < 4; ++ss)
        L += red_l[(qs + 4 * ss) * 16 + qq] * exp2f(red_m[(qs + 4 * ss) * 16 + qq] - M2);
    float inv = 1.f / L;
    float* op = out + ((size_t)b * T_SEQ + q0 + row) * 128 + d0;
    for (int j = 0; j < 8; ++j) op[j] = out_lds[row * 130 + d0 + j] * inv;
}

extern "C" void kernel_launch(void* const* d_in, const int* in_sizes, int n_in,
                              void* d_out, int out_size, void* d_ws, size_t ws_size,
                              hipStream_t stream)
{
    (void)in_sizes; (void)n_in; (void)out_size; (void)ws_size;
    const float* x  = (const float*)d_in[0];
    const float* Wq = (const float*)d_in[1];
    const float* bq = (const float*)d_in[2];
    const float* Wk = (const float*)d_in[3];
    const float* bk = (const float*)d_in[4];
    const float* Wv = (const float*)d_in[5];
    const float* bv = (const float*)d_in[6];
    float* out = (float*)d_out;

    // workspace: q f16 (4MB) | k f16 (4MB) | v^T f16 (4MB) = 12MB
    _Float16* qf = (_Float16*)d_ws;
    _Float16* kf = qf + (size_t)4 * T_SEQ * D_HEAD;
    _Float16* vt = kf + (size_t)4 * T_SEQ * D_HEAD;

    proj_kernel<<<dim3(256, 3), 256, 0, stream>>>(x, Wq, bq, Wk, bk, Wv, bv, qf, kf, vt);
    attn_kernel<<<dim3(256), 1024, 0, stream>>>(qf, kf, vt, out);
}

// Round 3
// 94.974 us; speedup vs baseline: 1.2325x; 1.2325x over previous
//
#include <hip/hip_runtime.h>
#include <cstdint>

typedef _Float16 half4_t __attribute__((ext_vector_type(4)));
typedef _Float16 half8_t __attribute__((ext_vector_type(8)));
typedef float floatx4 __attribute__((ext_vector_type(4)));

#define T_SEQ 4096
#define D_HEAD 128
#define SCALE_LOG2 0.12751742526f  // log2(e)/sqrt(128), folded into q at proj time

__device__ __forceinline__ void gload16(const void* src, void* dst_lds) {
    using gptr_t = const __attribute__((address_space(1))) unsigned int*;
    using lptr_t = __attribute__((address_space(3))) unsigned int*;
    __builtin_amdgcn_global_load_lds((gptr_t)(uintptr_t)src,
                                     (lptr_t)(unsigned int)(uintptr_t)dst_lds, 16, 0, 0);
}

// ---------------- QKV projection (MFMA f16, fp32 accumulate) ----------------
// grid: (B*T/64, 3), block 256. Writes q (pre-scaled by log2(e)/sqrt(D)), k as f16
// [B*T][128]; v transposed as f16 [B][128][T].
__global__ __launch_bounds__(256) void proj_kernel(
    const float* __restrict__ x,
    const float* __restrict__ Wq, const float* __restrict__ bq,
    const float* __restrict__ Wk, const float* __restrict__ bk,
    const float* __restrict__ Wv, const float* __restrict__ bv,
    _Float16* __restrict__ qf, _Float16* __restrict__ kf, _Float16* __restrict__ vt)
{
    __shared__ __align__(16) _Float16 Ws[128 * 136];
    __shared__ __align__(16) _Float16 xs[64 * 136];

    const int t = threadIdx.x;
    const int mat = blockIdx.y;
    const float* W = (mat == 0) ? Wq : (mat == 1) ? Wk : Wv;
    const float* bias = (mat == 0) ? bq : (mat == 1) ? bk : bv;
    const float osc = (mat == 0) ? SCALE_LOG2 : 1.0f;
    const int r0 = blockIdx.x * 64;

    {
        const int o = t >> 1;
        const int i0 = (t & 1) * 64;
        for (int jj = 0; jj < 8; ++jj) {
            floatx4 w0 = *reinterpret_cast<const floatx4*>(W + o * 128 + i0 + jj * 8);
            floatx4 w1 = *reinterpret_cast<const floatx4*>(W + o * 128 + i0 + jj * 8 + 4);
            half8_t h;
            h[0]=(_Float16)w0[0]; h[1]=(_Float16)w0[1]; h[2]=(_Float16)w0[2]; h[3]=(_Float16)w0[3];
            h[4]=(_Float16)w1[0]; h[5]=(_Float16)w1[1]; h[6]=(_Float16)w1[2]; h[7]=(_Float16)w1[3];
            *reinterpret_cast<half8_t*>(&Ws[o * 136 + i0 + jj * 8]) = h;
        }
    }
    {
        const int row = t >> 2;
        const int c0 = (t & 3) * 32;
        for (int jj = 0; jj < 4; ++jj) {
            floatx4 w0 = *reinterpret_cast<const floatx4*>(x + (size_t)(r0 + row) * 128 + c0 + jj * 8);
            floatx4 w1 = *reinterpret_cast<const floatx4*>(x + (size_t)(r0 + row) * 128 + c0 + jj * 8 + 4);
            half8_t h;
            h[0]=(_Float16)w0[0]; h[1]=(_Float16)w0[1]; h[2]=(_Float16)w0[2]; h[3]=(_Float16)w0[3];
            h[4]=(_Float16)w1[0]; h[5]=(_Float16)w1[1]; h[6]=(_Float16)w1[2]; h[7]=(_Float16)w1[3];
            *reinterpret_cast<half8_t*>(&xs[row * 136 + c0 + jj * 8]) = h;
        }
    }
    __syncthreads();

    const int w = t >> 6;
    const int lane = t & 63;
    const int lo = lane & 15, hi = lane >> 4;

    floatx4 acc[8] = {};
    for (int dc = 0; dc < 4; ++dc) {
        half8_t a8 = *reinterpret_cast<const half8_t*>(&xs[(w * 16 + lo) * 136 + dc * 32 + hi * 8]);
        for (int ot = 0; ot < 8; ++ot) {
            half8_t b8 = *reinterpret_cast<const half8_t*>(&Ws[(ot * 16 + lo) * 136 + dc * 32 + hi * 8]);
            acc[ot] = __builtin_amdgcn_mfma_f32_16x16x32_f16(a8, b8, acc[ot], 0, 0, 0);
        }
    }
    __syncthreads();

    float bb[8];
    for (int ot = 0; ot < 8; ++ot) bb[ot] = bias[ot * 16 + lo];

    if (mat < 2) {
        _Float16* ol = xs;
        for (int ot = 0; ot < 8; ++ot)
            for (int r = 0; r < 4; ++r)
                ol[(w * 16 + hi * 4 + r) * 136 + ot * 16 + lo] = (_Float16)((acc[ot][r] + bb[ot]) * osc);
        __syncthreads();
        _Float16* dst = (mat == 0) ? qf : kf;
        for (int i = 0; i < 4; ++i) {
            int c = t + 256 * i;
            int row = c >> 4, p = c & 15;
            half8_t v = *reinterpret_cast<const half8_t*>(&ol[row * 136 + p * 8]);
            *reinterpret_cast<half8_t*>(dst + (size_t)(r0 + row) * 128 + p * 8) = v;
        }
    } else {
        _Float16* vl = Ws;  // [128][72]
        for (int ot = 0; ot < 8; ++ot)
            for (int r = 0; r < 4; ++r)
                vl[(ot * 16 + lo) * 72 + w * 16 + hi * 4 + r] = (_Float16)(acc[ot][r] + bb[ot]);
        __syncthreads();
        const int b = r0 >> 12, tl0 = r0 & 4095;
        for (int i = 0; i < 4; ++i) {
            int c = t + 256 * i;
            int d = c >> 3, p = c & 7;
            half8_t v = *reinterpret_cast<const half8_t*>(&vl[d * 72 + p * 8]);
            *reinterpret_cast<half8_t*>(vt + ((size_t)(b * 128 + d)) * 4096 + tl0 + p * 8) = v;
        }
    }
}

// ---------------- flash attention ----------------
// 256 blocks x 512 threads (8 waves = 2 q-tiles x 4 kv-splits). Block owns 64 q rows.
// kv tile = 128 rows, double-buffered LDS (2 x 64KB: K 32KB swizzled + Vt 32KB swizzled),
// staged via global_load_lds w=16 with pre-swizzled global sources. One barrier per tile.
__global__ __launch_bounds__(512, 2) void attn_kernel(
    const _Float16* __restrict__ qf, const _Float16* __restrict__ kf,
    const _Float16* __restrict__ vt, float* __restrict__ out)
{
    __shared__ __align__(16) char smem[131072];

    const int tid = threadIdx.x;
    const int w = tid >> 6, lane = tid & 63;
    const int lo = lane & 15, hi = lane >> 4;
    const int qsub = w & 1, split = w >> 1;   // qsub: 32 q rows; split: 32 kv of 128-tile

    // XCD-aware swizzle: 8 XCDs x 32 contiguous wg -> one batch's KV per XCD pair
    const int bx = blockIdx.x;
    const int wg = (bx & 7) * 32 + (bx >> 3);
    const int b = wg >> 6;
    const int q0 = (wg & 63) * 64;

    const char* kbc = (const char*)(kf + (size_t)b * T_SEQ * 128);
    const char* vbc = (const char*)(vt + (size_t)b * 128 * T_SEQ);

    // loop-invariant staging offsets.
    // K LDS[row][slot] = K[t0+row][chunk = slot ^ (row&7)]   (rows 256B, 16 slots of 16B)
    // V LDS[d][slot]   = V^T[d][chunk = slot ^ ((d&7)<<1)]
    int koff[4], voff[4], kdst[4], vdst[4];
#pragma unroll
    for (int r = 0; r < 4; ++r) {
        int seg = w * 4 + r;
        int slot = lane & 15;
        int row = seg * 4 + (lane >> 4);
        koff[r] = row * 256 + ((slot ^ (row & 7)) << 4);
        kdst[r] = seg * 1024 + lane * 16;
        int d = row;
        voff[r] = d * (T_SEQ * 2) + ((slot ^ ((d & 7) << 1)) << 4);
        vdst[r] = 32768 + seg * 1024 + lane * 16;
    }

    // Q fragments (q pre-scaled by log2(e)/sqrt(D) at proj): enumeration dc*32+hi*8+j
    half8_t qfrag[2][4];
#pragma unroll
    for (int qt = 0; qt < 2; ++qt) {
        const _Float16* qrow = qf + ((size_t)b * T_SEQ + q0 + qsub * 32 + qt * 16 + lo) * 128;
#pragma unroll
        for (int dc = 0; dc < 4; ++dc)
            qfrag[qt][dc] = *reinterpret_cast<const half8_t*>(qrow + dc * 32 + hi * 8);
    }

    floatx4 accO[2][8] = {};
    float m_run[2] = {-1e30f, -1e30f}, l_run[2] = {0.f, 0.f};

    // prologue: stage tile 0 into buf0
#pragma unroll
    for (int r = 0; r < 4; ++r) {
        gload16(kbc + koff[r], smem + kdst[r]);
        gload16(vbc + voff[r], smem + vdst[r]);
    }
    __syncthreads();

    for (int t0 = 0; t0 < T_SEQ; t0 += 128) {
        const int cur = (t0 >> 7) & 1;
        char* buf = smem + (cur << 16);

        // prefetch next tile into the other buffer (issue FIRST, drain at barrier)
        if (t0 + 128 < T_SEQ) {
            char* nb = smem + ((cur ^ 1) << 16);
            const char* ks = kbc + (size_t)(t0 + 128) * 256;
            const char* vs = vbc + (size_t)(t0 + 128) * 2;
#pragma unroll
            for (int r = 0; r < 4; ++r) {
                gload16(ks + koff[r], nb + kdst[r]);
                gload16(vs + voff[r], nb + vdst[r]);
            }
        }

        // ---- QK^T: S^T[kv][q] for 32 kv x 32 q, K frags shared across both q-tiles
        floatx4 sac[2][2] = {};
#pragma unroll
        for (int s = 0; s < 2; ++s) {
            const char* kb0 = buf + (split * 32 + s * 16 + lo) * 256;
            const int rsw = lo & 7;
#pragma unroll
            for (int dc = 0; dc < 4; ++dc) {
                half8_t kf8 = *reinterpret_cast<const half8_t*>(kb0 + (((dc * 4 + hi) ^ rsw) << 4));
                sac[0][s] = __builtin_amdgcn_mfma_f32_16x16x32_f16(kf8, qfrag[0][dc], sac[0][s], 0, 0, 0);
                sac[1][s] = __builtin_amdgcn_mfma_f32_16x16x32_f16(kf8, qfrag[1][dc], sac[1][s], 0, 0, 0);
            }
        }

        // ---- online softmax (log2 domain; S already scaled). kv = kvl + s*16 + hi*4 + r, q = lo
        float bm[2];
        bool ok = true;
#pragma unroll
        for (int qt = 0; qt < 2; ++qt) {
            float m0 = fmaxf(fmaxf(sac[qt][0][0], sac[qt][0][1]), fmaxf(sac[qt][0][2], sac[qt][0][3]));
            float m1 = fmaxf(fmaxf(sac[qt][1][0], sac[qt][1][1]), fmaxf(sac[qt][1][2], sac[qt][1][3]));
            float m = fmaxf(m0, m1);
            m = fmaxf(m, __shfl_xor(m, 16));
            m = fmaxf(m, __shfl_xor(m, 32));
            bm[qt] = m;
            ok = ok && (m <= m_run[qt] + 4.0f);   // defer-max: P bounded by 2^4
        }
        if (!__all(ok)) {
#pragma unroll
            for (int qt = 0; qt < 2; ++qt) {
                float m_new = fmaxf(m_run[qt], bm[qt]);
                float alpha = exp2f(m_run[qt] - m_new);
                l_run[qt] *= alpha;
#pragma unroll
                for (int dt = 0; dt < 8; ++dt) accO[qt][dt] *= alpha;
                m_run[qt] = m_new;
            }
        }
        half8_t pa[2];
#pragma unroll
        for (int qt = 0; qt < 2; ++qt) {
            float bs = 0.f;
            half8_t pp;
#pragma unroll
            for (int s = 0; s < 2; ++s)
#pragma unroll
                for (int r = 0; r < 4; ++r) {
                    float pv = exp2f(sac[qt][s][r] - m_run[qt]);
                    bs += pv;
                    pp[s * 4 + r] = (_Float16)pv;
                }
            bs += __shfl_xor(bs, 16);
            bs += __shfl_xor(bs, 32);
            l_run[qt] += bs;
            pa[qt] = pp;
        }

        // ---- PV: O^T = V^T x P^T at K=32; k-enum g(hi,j) = {hi*4+j, 16+hi*4+(j-4)}
        const char* vbuf = buf + 32768;
#pragma unroll
        for (int dt = 0; dt < 8; ++dt) {
            int row = dt * 16 + lo;
            const char* vr = vbuf + row * 256;
            int sw = (row & 7) << 1;
            int c0 = split * 4 + (hi >> 1);
            half4_t va = *reinterpret_cast<const half4_t*>(vr + (((c0) ^ sw) << 4) + ((hi & 1) << 3));
            half4_t vb4 = *reinterpret_cast<const half4_t*>(vr + (((c0 + 2) ^ sw) << 4) + ((hi & 1) << 3));
            half8_t vfr;
            vfr[0]=va[0]; vfr[1]=va[1]; vfr[2]=va[2]; vfr[3]=va[3];
            vfr[4]=vb4[0]; vfr[5]=vb4[1]; vfr[6]=vb4[2]; vfr[7]=vb4[3];
            accO[0][dt] = __builtin_amdgcn_mfma_f32_16x16x32_f16(vfr, pa[0], accO[0][dt], 0, 0, 0);
            accO[1][dt] = __builtin_amdgcn_mfma_f32_16x16x32_f16(vfr, pa[1], accO[1][dt], 0, 0, 0);
        }
        __syncthreads();
    }

    // ---- merge 4 kv-splits ----
    float* red_m = reinterpret_cast<float*>(smem + 65536);          // [4][64]
    float* red_l = reinterpret_cast<float*>(smem + 65536 + 1024);   // [4][64]
    int row64[2]; float fac[2];
#pragma unroll
    for (int qt = 0; qt < 2; ++qt) row64[qt] = qsub * 32 + qt * 16 + lo;
    if (hi == 0) {
#pragma unroll
        for (int qt = 0; qt < 2; ++qt) {
            red_m[split * 64 + row64[qt]] = m_run[qt];
            red_l[split * 64 + row64[qt]] = l_run[qt];
        }
    }
    __syncthreads();
#pragma unroll
    for (int qt = 0; qt < 2; ++qt) {
        float M = -1e30f;
#pragma unroll
        for (int s = 0; s < 4; ++s) M = fmaxf(M, red_m[s * 64 + row64[qt]]);
        float L = 0.f;
#pragma unroll
        for (int s = 0; s < 4; ++s) L += red_l[s * 64 + row64[qt]] * exp2f(red_m[s * 64 + row64[qt]] - M);
        fac[qt] = exp2f(m_run[qt] - M) / L;   // rescale + normalize folded
    }
    float* out_lds = reinterpret_cast<float*>(smem);  // [64][132] fp32 (buf0, dead)
    for (int s = 0; s < 4; ++s) {
        if (split == s) {
#pragma unroll
            for (int qt = 0; qt < 2; ++qt)
#pragma unroll
                for (int dt = 0; dt < 8; ++dt)
#pragma unroll
                    for (int r = 0; r < 4; ++r) {
                        int d = dt * 16 + hi * 4 + r;
                        float v = accO[qt][dt][r] * fac[qt];
                        float* p = &out_lds[row64[qt] * 132 + d];
                        if (s == 0) *p = v; else *p += v;
                    }
        }
        __syncthreads();
    }
    {
        int row = tid >> 3, d0 = (tid & 7) * 16;
        float* op = out + ((size_t)b * T_SEQ + q0 + row) * 128 + d0;
#pragma unroll
        for (int j = 0; j < 4; ++j) {
            float4 v;
            v.x = out_lds[row * 132 + d0 + j * 4 + 0];
            v.y = out_lds[row * 132 + d0 + j * 4 + 1];
            v.z = out_lds[row * 132 + d0 + j * 4 + 2];
            v.w = out_lds[row * 132 + d0 + j * 4 + 3];
            *reinterpret_cast<float4*>(op + j * 4) = v;
        }
    }
}

extern "C" void kernel_launch(void* const* d_in, const int* in_sizes, int n_in,
                              void* d_out, int out_size, void* d_ws, size_t ws_size,
                              hipStream_t stream)
{
    (void)in_sizes; (void)n_in; (void)out_size; (void)ws_size;
    const float* x  = (const float*)d_in[0];
    const float* Wq = (const float*)d_in[1];
    const float* bq = (const float*)d_in[2];
    const float* Wk = (const float*)d_in[3];
    const float* bk = (const float*)d_in[4];
    const float* Wv = (const float*)d_in[5];
    const float* bv = (const float*)d_in[6];
    float* out = (float*)d_out;

    _Float16* qf = (_Float16*)d_ws;
    _Float16* kf = qf + (size_t)4 * T_SEQ * D_HEAD;
    _Float16* vt = kf + (size_t)4 * T_SEQ * D_HEAD;

    proj_kernel<<<dim3(256, 3), 256, 0, stream>>>(x, Wq, bq, Wk, bk, Wv, bv, qf, kf, vt);
    attn_kernel<<<dim3(256), 512, 0, stream>>>(qf, kf, vt, out);
}

// Round 4
// 92.051 us; speedup vs baseline: 1.2716x; 1.0317x over previous
//
#include <hip/hip_runtime.h>
#include <cstdint>

typedef _Float16 half4_t __attribute__((ext_vector_type(4)));
typedef _Float16 half8_t __attribute__((ext_vector_type(8)));
typedef float floatx4 __attribute__((ext_vector_type(4)));

#define T_SEQ 4096
#define D_HEAD 128
#define SCALE_LOG2 0.12751742526f  // log2(e)/sqrt(128), folded into q at proj time

__device__ __forceinline__ void gload16(const void* src, void* dst_lds) {
    using gptr_t = const __attribute__((address_space(1))) unsigned int*;
    using lptr_t = __attribute__((address_space(3))) unsigned int*;
    __builtin_amdgcn_global_load_lds((gptr_t)(uintptr_t)src,
                                     (lptr_t)(unsigned int)(uintptr_t)dst_lds, 16, 0, 0);
}

// ---------------- QKV projection (MFMA f16, fp32 accumulate) ----------------
__global__ __launch_bounds__(256) void proj_kernel(
    const float* __restrict__ x,
    const float* __restrict__ Wq, const float* __restrict__ bq,
    const float* __restrict__ Wk, const float* __restrict__ bk,
    const float* __restrict__ Wv, const float* __restrict__ bv,
    _Float16* __restrict__ qf, _Float16* __restrict__ kf, _Float16* __restrict__ vt)
{
    __shared__ __align__(16) _Float16 Ws[128 * 136];
    __shared__ __align__(16) _Float16 xs[64 * 136];

    const int t = threadIdx.x;
    const int mat = blockIdx.y;
    const float* W = (mat == 0) ? Wq : (mat == 1) ? Wk : Wv;
    const float* bias = (mat == 0) ? bq : (mat == 1) ? bk : bv;
    const float osc = (mat == 0) ? SCALE_LOG2 : 1.0f;
    const int r0 = blockIdx.x * 64;

    {
        const int o = t >> 1;
        const int i0 = (t & 1) * 64;
        for (int jj = 0; jj < 8; ++jj) {
            floatx4 w0 = *reinterpret_cast<const floatx4*>(W + o * 128 + i0 + jj * 8);
            floatx4 w1 = *reinterpret_cast<const floatx4*>(W + o * 128 + i0 + jj * 8 + 4);
            half8_t h;
            h[0]=(_Float16)w0[0]; h[1]=(_Float16)w0[1]; h[2]=(_Float16)w0[2]; h[3]=(_Float16)w0[3];
            h[4]=(_Float16)w1[0]; h[5]=(_Float16)w1[1]; h[6]=(_Float16)w1[2]; h[7]=(_Float16)w1[3];
            *reinterpret_cast<half8_t*>(&Ws[o * 136 + i0 + jj * 8]) = h;
        }
    }
    {
        const int row = t >> 2;
        const int c0 = (t & 3) * 32;
        for (int jj = 0; jj < 4; ++jj) {
            floatx4 w0 = *reinterpret_cast<const floatx4*>(x + (size_t)(r0 + row) * 128 + c0 + jj * 8);
            floatx4 w1 = *reinterpret_cast<const floatx4*>(x + (size_t)(r0 + row) * 128 + c0 + jj * 8 + 4);
            half8_t h;
            h[0]=(_Float16)w0[0]; h[1]=(_Float16)w0[1]; h[2]=(_Float16)w0[2]; h[3]=(_Float16)w0[3];
            h[4]=(_Float16)w1[0]; h[5]=(_Float16)w1[1]; h[6]=(_Float16)w1[2]; h[7]=(_Float16)w1[3];
            *reinterpret_cast<half8_t*>(&xs[row * 136 + c0 + jj * 8]) = h;
        }
    }
    __syncthreads();

    const int w = t >> 6;
    const int lane = t & 63;
    const int lo = lane & 15, hi = lane >> 4;

    floatx4 acc[8] = {};
    for (int dc = 0; dc < 4; ++dc) {
        half8_t a8 = *reinterpret_cast<const half8_t*>(&xs[(w * 16 + lo) * 136 + dc * 32 + hi * 8]);
        for (int ot = 0; ot < 8; ++ot) {
            half8_t b8 = *reinterpret_cast<const half8_t*>(&Ws[(ot * 16 + lo) * 136 + dc * 32 + hi * 8]);
            acc[ot] = __builtin_amdgcn_mfma_f32_16x16x32_f16(a8, b8, acc[ot], 0, 0, 0);
        }
    }
    __syncthreads();

    float bb[8];
    for (int ot = 0; ot < 8; ++ot) bb[ot] = bias[ot * 16 + lo];

    if (mat < 2) {
        _Float16* ol = xs;
        for (int ot = 0; ot < 8; ++ot)
            for (int r = 0; r < 4; ++r)
                ol[(w * 16 + hi * 4 + r) * 136 + ot * 16 + lo] = (_Float16)((acc[ot][r] + bb[ot]) * osc);
        __syncthreads();
        _Float16* dst = (mat == 0) ? qf : kf;
        for (int i = 0; i < 4; ++i) {
            int c = t + 256 * i;
            int row = c >> 4, p = c & 15;
            half8_t v = *reinterpret_cast<const half8_t*>(&ol[row * 136 + p * 8]);
            *reinterpret_cast<half8_t*>(dst + (size_t)(r0 + row) * 128 + p * 8) = v;
        }
    } else {
        _Float16* vl = Ws;  // [128][72]
        for (int ot = 0; ot < 8; ++ot)
            for (int r = 0; r < 4; ++r)
                vl[(ot * 16 + lo) * 72 + w * 16 + hi * 4 + r] = (_Float16)(acc[ot][r] + bb[ot]);
        __syncthreads();
        const int b = r0 >> 12, tl0 = r0 & 4095;
        for (int i = 0; i < 4; ++i) {
            int c = t + 256 * i;
            int d = c >> 3, p = c & 7;
            half8_t v = *reinterpret_cast<const half8_t*>(&vl[d * 72 + p * 8]);
            *reinterpret_cast<half8_t*>(vt + ((size_t)(b * 128 + d)) * 4096 + tl0 + p * 8) = v;
        }
    }
}

// ---------------- flash attention ----------------
// 256 blocks x 1024 threads = 16 waves: 4 qsub (16 q rows) x 4 kv-splits (32 kv).
// kv tile = 128, double-buffered LDS 2 x (K 32KB + V 32KB) = 128KB, staged via
// global_load_lds w=16 with pre-swizzled global sources. One barrier per tile.
// 16 waves/CU = 4/SIMD for latency hiding.
__global__ __launch_bounds__(1024) void attn_kernel(
    const _Float16* __restrict__ qf, const _Float16* __restrict__ kf,
    const _Float16* __restrict__ vt, float* __restrict__ out)
{
    __shared__ __align__(16) char smem[131072];

    const int tid = threadIdx.x;
    const int w = tid >> 6, lane = tid & 63;
    const int lo = lane & 15, hi = lane >> 4;
    const int qsub = w & 3, split = w >> 2;

    // XCD-aware swizzle
    const int bx = blockIdx.x;
    const int wg = (bx & 7) * 32 + (bx >> 3);
    const int b = wg >> 6;
    const int q0 = (wg & 63) * 64;

    const char* kbc = (const char*)(kf + (size_t)b * T_SEQ * 128);
    const char* vbc = (const char*)(vt + (size_t)b * 128 * T_SEQ);

    // staging offsets: both K and V swizzled chunk ^= (row&7) (16B chunks, 256B rows)
    int koff[2], voff[2], kdst[2], vdst[2];
#pragma unroll
    for (int r = 0; r < 2; ++r) {
        int seg = w * 2 + r;
        int slot = lane & 15;
        int row = seg * 4 + (lane >> 4);
        koff[r] = row * 256 + ((slot ^ (row & 7)) << 4);
        kdst[r] = seg * 1024 + lane * 16;
        voff[r] = row * (T_SEQ * 2) + ((slot ^ (row & 7)) << 4);
        vdst[r] = 32768 + seg * 1024 + lane * 16;
    }

    // Q fragments (pre-scaled): enumeration dc*32 + hi*8 + j, matches K-side
    half8_t qfrag[4];
    {
        const _Float16* qrow = qf + ((size_t)b * T_SEQ + q0 + qsub * 16 + lo) * 128;
#pragma unroll
        for (int dc = 0; dc < 4; ++dc)
            qfrag[dc] = *reinterpret_cast<const half8_t*>(qrow + dc * 32 + hi * 8);
    }

    floatx4 accO[8] = {};
    float m_run = -1e30f, l_run = 0.f;

    // prologue: stage tile 0 into buf0
#pragma unroll
    for (int r = 0; r < 2; ++r) {
        gload16(kbc + koff[r], smem + kdst[r]);
        gload16(vbc + voff[r], smem + vdst[r]);
    }
    __syncthreads();

    for (int t0 = 0; t0 < T_SEQ; t0 += 128) {
        const int cur = (t0 >> 7) & 1;
        char* buf = smem + (cur << 16);

        // prefetch next tile (issue first; drained by the end-of-loop barrier)
        if (t0 + 128 < T_SEQ) {
            char* nb = smem + ((cur ^ 1) << 16);
            const char* ks = kbc + (size_t)(t0 + 128) * 256;
            const char* vs = vbc + (size_t)(t0 + 128) * 2;
#pragma unroll
            for (int r = 0; r < 2; ++r) {
                gload16(ks + koff[r], nb + kdst[r]);
                gload16(vs + voff[r], nb + vdst[r]);
            }
        }

        // ---- QK^T: S^T[kv][q], 32 kv x 16 q per wave
        floatx4 sac[2] = {};
        __builtin_amdgcn_s_setprio(1);
#pragma unroll
        for (int s = 0; s < 2; ++s) {
            const char* kb0 = buf + (split * 32 + s * 16 + lo) * 256;
            const int rsw = lo & 7;
#pragma unroll
            for (int dc = 0; dc < 4; ++dc) {
                half8_t kf8 = *reinterpret_cast<const half8_t*>(kb0 + (((dc * 4 + hi) ^ rsw) << 4));
                sac[s] = __builtin_amdgcn_mfma_f32_16x16x32_f16(kf8, qfrag[dc], sac[s], 0, 0, 0);
            }
        }
        __builtin_amdgcn_s_setprio(0);

        // ---- online softmax (log2 domain). kv = split*32 + s*16 + hi*4 + r, q = lo
        float m = fmaxf(fmaxf(fmaxf(sac[0][0], sac[0][1]), fmaxf(sac[0][2], sac[0][3])),
                        fmaxf(fmaxf(sac[1][0], sac[1][1]), fmaxf(sac[1][2], sac[1][3])));
        m = fmaxf(m, __shfl_xor(m, 16));
        m = fmaxf(m, __shfl_xor(m, 32));
        bool ok = (m <= m_run + 4.0f);   // defer-max: P bounded by 2^4
        if (!__all(ok)) {
            float m_new = fmaxf(m_run, m);
            float alpha = exp2f(m_run - m_new);
            l_run *= alpha;
#pragma unroll
            for (int dt = 0; dt < 8; ++dt) accO[dt] *= alpha;
            m_run = m_new;
        }
        half8_t pa;
        float bs = 0.f;
#pragma unroll
        for (int s = 0; s < 2; ++s)
#pragma unroll
            for (int r = 0; r < 4; ++r) {
                float pv = exp2f(sac[s][r] - m_run);
                bs += pv;
                pa[s * 4 + r] = (_Float16)pv;
            }
        bs += __shfl_xor(bs, 16);
        bs += __shfl_xor(bs, 32);
        l_run += bs;

        // ---- PV: O^T = V^T x P^T at K=32; V k-enum matches pa's
        const char* vbuf = buf + 32768;
        __builtin_amdgcn_s_setprio(1);
#pragma unroll
        for (int dt = 0; dt < 8; ++dt) {
            int row = dt * 16 + lo;
            const char* vr = vbuf + row * 256;
            int sw = lo & 7;
            int c0 = split * 4 + (hi >> 1);
            half4_t va  = *reinterpret_cast<const half4_t*>(vr + ((c0 ^ sw) << 4) + ((hi & 1) << 3));
            half4_t vb4 = *reinterpret_cast<const half4_t*>(vr + (((c0 + 2) ^ sw) << 4) + ((hi & 1) << 3));
            half8_t vfr;
            vfr[0]=va[0]; vfr[1]=va[1]; vfr[2]=va[2]; vfr[3]=va[3];
            vfr[4]=vb4[0]; vfr[5]=vb4[1]; vfr[6]=vb4[2]; vfr[7]=vb4[3];
            accO[dt] = __builtin_amdgcn_mfma_f32_16x16x32_f16(vfr, pa, accO[dt], 0, 0, 0);
        }
        __builtin_amdgcn_s_setprio(0);
        __syncthreads();
    }

    // ---- merge 4 kv-splits ----
    float* red_m = reinterpret_cast<float*>(smem + 40960);   // [4][64]
    float* red_l = reinterpret_cast<float*>(smem + 43008);   // [4][64]
    const int row16 = qsub * 16 + lo;
    if (hi == 0) {
        red_m[split * 64 + row16] = m_run;
        red_l[split * 64 + row16] = l_run;
    }
    __syncthreads();
    float M = -1e30f;
#pragma unroll
    for (int s = 0; s < 4; ++s) M = fmaxf(M, red_m[s * 64 + row16]);
    float L = 0.f;
#pragma unroll
    for (int s = 0; s < 4; ++s) L += red_l[s * 64 + row16] * exp2f(red_m[s * 64 + row16] - M);
    const float fac = exp2f(m_run - M) / L;   // rescale + normalize folded

    float* out_lds = reinterpret_cast<float*>(smem);  // [64][132] fp32 = 33792B
    for (int s = 0; s < 4; ++s) {
        if (split == s) {
#pragma unroll
            for (int dt = 0; dt < 8; ++dt)
#pragma unroll
                for (int r = 0; r < 4; ++r) {
                    int d = dt * 16 + hi * 4 + r;
                    float v = accO[dt][r] * fac;
                    float* p = &out_lds[row16 * 132 + d];
                    if (s == 0) *p = v; else *p += v;
                }
        }
        __syncthreads();
    }
    {
        int row = tid >> 4, d0 = (tid & 15) * 8;
        float* op = out + ((size_t)b * T_SEQ + q0 + row) * 128 + d0;
#pragma unroll
        for (int j = 0; j < 2; ++j) {
            float4 v;
            v.x = out_lds[row * 132 + d0 + j * 4 + 0];
            v.y = out_lds[row * 132 + d0 + j * 4 + 1];
            v.z = out_lds[row * 132 + d0 + j * 4 + 2];
            v.w = out_lds[row * 132 + d0 + j * 4 + 3];
            *reinterpret_cast<float4*>(op + j * 4) = v;
        }
    }
}

extern "C" void kernel_launch(void* const* d_in, const int* in_sizes, int n_in,
                              void* d_out, int out_size, void* d_ws, size_t ws_size,
                              hipStream_t stream)
{
    (void)in_sizes; (void)n_in; (void)out_size; (void)ws_size;
    const float* x  = (const float*)d_in[0];
    const float* Wq = (const float*)d_in[1];
    const float* bq = (const float*)d_in[2];
    const float* Wk = (const float*)d_in[3];
    const float* bk = (const float*)d_in[4];
    const float* Wv = (const float*)d_in[5];
    const float* bv = (const float*)d_in[6];
    float* out = (float*)d_out;

    _Float16* qf = (_Float16*)d_ws;
    _Float16* kf = qf + (size_t)4 * T_SEQ * D_HEAD;
    _Float16* vt = kf + (size_t)4 * T_SEQ * D_HEAD;

    proj_kernel<<<dim3(256, 3), 256, 0, stream>>>(x, Wq, bq, Wk, bk, Wv, bv, qf, kf, vt);
    attn_kernel<<<dim3(256), 1024, 0, stream>>>(qf, kf, vt, out);
}

// Round 6
// 85.293 us; speedup vs baseline: 1.3724x; 1.0792x over previous
//
#include <hip/hip_runtime.h>
#include <cstdint>

typedef _Float16 half2_t __attribute__((ext_vector_type(2)));
typedef _Float16 half4_t __attribute__((ext_vector_type(4)));
typedef _Float16 half8_t __attribute__((ext_vector_type(8)));
typedef float floatx4 __attribute__((ext_vector_type(4)));

#define T_SEQ 4096
#define D_HEAD 128
#define SCALE_LOG2 0.12751742526f  // log2(e)/sqrt(128), folded into q at proj time

__device__ __forceinline__ void gload16(const void* src, void* dst_lds) {
    using gptr_t = const __attribute__((address_space(1))) unsigned int*;
    using lptr_t = __attribute__((address_space(3))) unsigned int*;
    __builtin_amdgcn_global_load_lds((gptr_t)(uintptr_t)src,
                                     (lptr_t)(unsigned int)(uintptr_t)dst_lds, 16, 0, 0);
}

// ---------------- QKV projection (MFMA f16, fp32 accumulate) ----------------
__global__ __launch_bounds__(256) void proj_kernel(
    const float* __restrict__ x,
    const float* __restrict__ Wq, const float* __restrict__ bq,
    const float* __restrict__ Wk, const float* __restrict__ bk,
    const float* __restrict__ Wv, const float* __restrict__ bv,
    _Float16* __restrict__ qf, _Float16* __restrict__ kf, _Float16* __restrict__ vt)
{
    __shared__ __align__(16) _Float16 Ws[128 * 136];
    __shared__ __align__(16) _Float16 xs[64 * 136];

    const int t = threadIdx.x;
    const int mat = blockIdx.y;
    const float* W = (mat == 0) ? Wq : (mat == 1) ? Wk : Wv;
    const float* bias = (mat == 0) ? bq : (mat == 1) ? bk : bv;
    const float osc = (mat == 0) ? SCALE_LOG2 : 1.0f;
    const int r0 = blockIdx.x * 64;

    {
        const int o = t >> 1;
        const int i0 = (t & 1) * 64;
        for (int jj = 0; jj < 8; ++jj) {
            floatx4 w0 = *reinterpret_cast<const floatx4*>(W + o * 128 + i0 + jj * 8);
            floatx4 w1 = *reinterpret_cast<const floatx4*>(W + o * 128 + i0 + jj * 8 + 4);
            half8_t h;
            h[0]=(_Float16)w0[0]; h[1]=(_Float16)w0[1]; h[2]=(_Float16)w0[2]; h[3]=(_Float16)w0[3];
            h[4]=(_Float16)w1[0]; h[5]=(_Float16)w1[1]; h[6]=(_Float16)w1[2]; h[7]=(_Float16)w1[3];
            *reinterpret_cast<half8_t*>(&Ws[o * 136 + i0 + jj * 8]) = h;
        }
    }
    {
        const int row = t >> 2;
        const int c0 = (t & 3) * 32;
        for (int jj = 0; jj < 4; ++jj) {
            floatx4 w0 = *reinterpret_cast<const floatx4*>(x + (size_t)(r0 + row) * 128 + c0 + jj * 8);
            floatx4 w1 = *reinterpret_cast<const floatx4*>(x + (size_t)(r0 + row) * 128 + c0 + jj * 8 + 4);
            half8_t h;
            h[0]=(_Float16)w0[0]; h[1]=(_Float16)w0[1]; h[2]=(_Float16)w0[2]; h[3]=(_Float16)w0[3];
            h[4]=(_Float16)w1[0]; h[5]=(_Float16)w1[1]; h[6]=(_Float16)w1[2]; h[7]=(_Float16)w1[3];
            *reinterpret_cast<half8_t*>(&xs[row * 136 + c0 + jj * 8]) = h;
        }
    }
    __syncthreads();

    const int w = t >> 6;
    const int lane = t & 63;
    const int lo = lane & 15, hi = lane >> 4;

    floatx4 acc[8] = {};
    for (int dc = 0; dc < 4; ++dc) {
        half8_t a8 = *reinterpret_cast<const half8_t*>(&xs[(w * 16 + lo) * 136 + dc * 32 + hi * 8]);
        for (int ot = 0; ot < 8; ++ot) {
            half8_t b8 = *reinterpret_cast<const half8_t*>(&Ws[(ot * 16 + lo) * 136 + dc * 32 + hi * 8]);
            acc[ot] = __builtin_amdgcn_mfma_f32_16x16x32_f16(a8, b8, acc[ot], 0, 0, 0);
        }
    }
    __syncthreads();

    float bb[8];
    for (int ot = 0; ot < 8; ++ot) bb[ot] = bias[ot * 16 + lo];

    if (mat < 2) {
        _Float16* ol = xs;
        for (int ot = 0; ot < 8; ++ot)
            for (int r = 0; r < 4; ++r)
                ol[(w * 16 + hi * 4 + r) * 136 + ot * 16 + lo] = (_Float16)((acc[ot][r] + bb[ot]) * osc);
        __syncthreads();
        _Float16* dst = (mat == 0) ? qf : kf;
        for (int i = 0; i < 4; ++i) {
            int c = t + 256 * i;
            int row = c >> 4, p = c & 15;
            half8_t v = *reinterpret_cast<const half8_t*>(&ol[row * 136 + p * 8]);
            *reinterpret_cast<half8_t*>(dst + (size_t)(r0 + row) * 128 + p * 8) = v;
        }
    } else {
        _Float16* vl = Ws;  // [128][72]
        for (int ot = 0; ot < 8; ++ot)
            for (int r = 0; r < 4; ++r)
                vl[(ot * 16 + lo) * 72 + w * 16 + hi * 4 + r] = (_Float16)(acc[ot][r] + bb[ot]);
        __syncthreads();
        const int b = r0 >> 12, tl0 = r0 & 4095;
        for (int i = 0; i < 4; ++i) {
            int c = t + 256 * i;
            int d = c >> 3, p = c & 7;
            half8_t v = *reinterpret_cast<const half8_t*>(&vl[d * 72 + p * 8]);
            *reinterpret_cast<half8_t*>(vt + ((size_t)(b * 128 + d)) * 4096 + tl0 + p * 8) = v;
        }
    }
}

// ---------------- flash attention ----------------
// 256 blocks x 512 threads = 8 waves: 2 q-groups (32 q as 2x16) x 4 kv-splits (32 kv).
// kv tile = 128, double-buffered 2x64KB LDS. K staged via global_load_lds (pre-swizzled
// source); V staged via registers into an interleaved layout so each PV fragment is a
// single ds_read_b128. Tile loop unrolled x2 (static buffer offsets -> hoisted addrs).
__global__ __launch_bounds__(512, 1) void attn_kernel(
    const _Float16* __restrict__ qf, const _Float16* __restrict__ kf,
    const _Float16* __restrict__ vt, float* __restrict__ out)
{
    __shared__ __align__(16) char smem[131072];

    const int tid = threadIdx.x;
    const int w = tid >> 6, lane = tid & 63;
    const int lo = lane & 15, hi = lane >> 4;
    const int qt2 = w & 1, split = w >> 1;

    // XCD-aware swizzle
    const int bx = blockIdx.x;
    const int wg = (bx & 7) * 32 + (bx >> 3);
    const int b = wg >> 6;
    const int q0 = (wg & 63) * 64;

    const char* kbc = (const char*)(kf + (size_t)b * T_SEQ * 128);
    const char* vbc = (const char*)(vt + (size_t)b * 128 * T_SEQ);

    // ---- K staging: 4 x gload16 per thread, LDS[row][slot] = K[row][slot ^ (row&7)]
    int koff[4], kdst[4];
#pragma unroll
    for (int r = 0; r < 4; ++r) {
        int seg = w * 4 + r;
        int slot = lane & 15;
        int row = seg * 4 + (lane >> 4);
        koff[r] = row * 256 + ((slot ^ (row & 7)) << 4);
        kdst[r] = seg * 1024 + lane * 16;
    }

    // ---- V staging (reg -> interleaved LDS). Thread handles (d_i = tid>>4 + 32i, c = tid&15).
    // Chunk c (kv c*8..c*8+7) splits into unit u=(c>>2)*4+(c&1)*2 (+1), byte off=(c&2)*4.
    // LDS unit slot is XOR-swizzled by d&7. Read back: one b128 per (d-row, split*4+hi).
    const int vc = tid & 15;
    const int vua = ((vc >> 2) << 2) + ((vc & 1) << 1);
    const int voffb = (vc & 2) << 2;
    int vgo[4], vwa[4], vwb[4];
#pragma unroll
    for (int i = 0; i < 4; ++i) {
        int d = (tid >> 4) + 32 * i;
        vgo[i] = d * (T_SEQ * 2) + vc * 16;
        vwa[i] = 32768 + d * 256 + (((vua)     ^ (d & 7)) << 4) + voffb;
        vwb[i] = 32768 + d * 256 + (((vua + 1) ^ (d & 7)) << 4) + voffb;
    }

    // ---- LDS read offsets (loop-invariant, buffer offset added in-loop as constant)
    int kro[2][4];
#pragma unroll
    for (int s = 0; s < 2; ++s)
#pragma unroll
        for (int dc = 0; dc < 4; ++dc)
            kro[s][dc] = (split * 32 + s * 16 + lo) * 256 + ((((dc * 4 + hi)) ^ (lo & 7)) << 4);
    int vro[8];
#pragma unroll
    for (int dt = 0; dt < 8; ++dt)
        vro[dt] = 32768 + (dt * 16 + lo) * 256 + (((split * 4 + hi) ^ (lo & 7)) << 4);

    // ---- Q fragments (pre-scaled): d-enum dc*32 + hi*8 + j, identical to K-side
    half8_t qfrag[2][4];
#pragma unroll
    for (int qt = 0; qt < 2; ++qt) {
        const _Float16* qrow = qf + ((size_t)b * T_SEQ + q0 + qt2 * 32 + qt * 16 + lo) * 128;
#pragma unroll
        for (int dc = 0; dc < 4; ++dc)
            qfrag[qt][dc] = *reinterpret_cast<const half8_t*>(qrow + dc * 32 + hi * 8);
    }

    floatx4 accO[2][8] = {};
    float m_run[2] = {-1e30f, -1e30f}, l_run[2] = {0.f, 0.f};

    // ---- prologue: stage tile 0 into buf0
#pragma unroll
    for (int r = 0; r < 4; ++r) gload16(kbc + koff[r], smem + kdst[r]);
    {
        uint4 vreg[4];
#pragma unroll
        for (int i = 0; i < 4; ++i) vreg[i] = *reinterpret_cast<const uint4*>(vbc + vgo[i]);
#pragma unroll
        for (int i = 0; i < 4; ++i) {
            *reinterpret_cast<uint2*>(smem + vwa[i]) = make_uint2(vreg[i].x, vreg[i].y);
            *reinterpret_cast<uint2*>(smem + vwb[i]) = make_uint2(vreg[i].z, vreg[i].w);
        }
    }
    __syncthreads();

#define TILE(T0, CUR, NXT, PF) do {                                                    \
    uint4 vreg[4];                                                                     \
    if (PF) {                                                                          \
        const char* vs = vbc + (size_t)((T0) + 128) * 2;                               \
        _Pragma("unroll")                                                              \
        for (int i = 0; i < 4; ++i)                                                    \
            vreg[i] = *reinterpret_cast<const uint4*>(vs + vgo[i]);                    \
        const char* ks = kbc + (size_t)((T0) + 128) * 256;                             \
        _Pragma("unroll")                                                              \
        for (int r = 0; r < 4; ++r) gload16(ks + koff[r], smem + (NXT) + kdst[r]);     \
    }                                                                                  \
    const char* bufc = smem + (CUR);                                                   \
    floatx4 sac[2][2] = {};                                                            \
    __builtin_amdgcn_s_setprio(1);                                                     \
    _Pragma("unroll")                                                                  \
    for (int s = 0; s < 2; ++s) {                                                      \
        _Pragma("unroll")                                                              \
        for (int dc = 0; dc < 4; ++dc) {                                               \
            half8_t kf8 = *reinterpret_cast<const half8_t*>(bufc + kro[s][dc]);        \
            sac[0][s] = __builtin_amdgcn_mfma_f32_16x16x32_f16(kf8, qfrag[0][dc], sac[0][s], 0, 0, 0); \
            sac[1][s] = __builtin_amdgcn_mfma_f32_16x16x32_f16(kf8, qfrag[1][dc], sac[1][s], 0, 0, 0); \
        }                                                                              \
    }                                                                                  \
    __builtin_amdgcn_s_setprio(0);                                                     \
    float bm[2];                                                                       \
    bool ok = true;                                                                    \
    _Pragma("unroll")                                                                  \
    for (int qt = 0; qt < 2; ++qt) {                                                   \
        float m0 = fmaxf(fmaxf(sac[qt][0][0], sac[qt][0][1]), fmaxf(sac[qt][0][2], sac[qt][0][3])); \
        float m1 = fmaxf(fmaxf(sac[qt][1][0], sac[qt][1][1]), fmaxf(sac[qt][1][2], sac[qt][1][3])); \
        float m = fmaxf(m0, m1);                                                       \
        m = fmaxf(m, __shfl_xor(m, 16));                                               \
        m = fmaxf(m, __shfl_xor(m, 32));                                               \
        bm[qt] = m;                                                                    \
        ok = ok && (m <= m_run[qt] + 4.0f);                                            \
    }                                                                                  \
    if (!__all(ok)) {                                                                  \
        _Pragma("unroll")                                                              \
        for (int qt = 0; qt < 2; ++qt) {                                               \
            float m_new = fmaxf(m_run[qt], bm[qt]);                                    \
            float alpha = exp2f(m_run[qt] - m_new);                                    \
            l_run[qt] *= alpha;                                                        \
            _Pragma("unroll")                                                          \
            for (int dt = 0; dt < 8; ++dt) accO[qt][dt] *= alpha;                      \
            m_run[qt] = m_new;                                                         \
        }                                                                              \
    }                                                                                  \
    half8_t pa[2];                                                                     \
    _Pragma("unroll")                                                                  \
    for (int qt = 0; qt < 2; ++qt) {                                                   \
        float pv[8];                                                                   \
        float bs = 0.f;                                                                \
        _Pragma("unroll")                                                              \
        for (int j = 0; j < 8; ++j) {                                                  \
            int s = j >> 2, r = j & 3;                                                 \
            pv[j] = exp2f(sac[qt][s][r] - m_run[qt]);                                  \
            bs += pv[j];                                                               \
        }                                                                              \
        bs += __shfl_xor(bs, 16);                                                      \
        bs += __shfl_xor(bs, 32);                                                      \
        l_run[qt] += bs;                                                               \
        _Pragma("unroll")                                                              \
        for (int j2 = 0; j2 < 4; ++j2) {                                               \
            half2_t h2 = __builtin_bit_cast(half2_t,                                   \
                __builtin_amdgcn_cvt_pkrtz(pv[j2 * 2], pv[j2 * 2 + 1]));               \
            pa[qt][j2 * 2] = h2[0];                                                    \
            pa[qt][j2 * 2 + 1] = h2[1];                                                \
        }                                                                              \
    }                                                                                  \
    __builtin_amdgcn_s_setprio(1);                                                     \
    _Pragma("unroll")                                                                  \
    for (int dt = 0; dt < 8; ++dt) {                                                   \
        half8_t vfr = *reinterpret_cast<const half8_t*>(bufc + vro[dt]);               \
        accO[0][dt] = __builtin_amdgcn_mfma_f32_16x16x32_f16(vfr, pa[0], accO[0][dt], 0, 0, 0); \
        accO[1][dt] = __builtin_amdgcn_mfma_f32_16x16x32_f16(vfr, pa[1], accO[1][dt], 0, 0, 0); \
    }                                                                                  \
    __builtin_amdgcn_s_setprio(0);                                                     \
    if (PF) {                                                                          \
        _Pragma("unroll")                                                              \
        for (int i = 0; i < 4; ++i) {                                                  \
            *reinterpret_cast<uint2*>(smem + (NXT) + vwa[i]) = make_uint2(vreg[i].x, vreg[i].y); \
            *reinterpret_cast<uint2*>(smem + (NXT) + vwb[i]) = make_uint2(vreg[i].z, vreg[i].w); \
        }                                                                              \
    }                                                                                  \
    __syncthreads();                                                                   \
} while (0)

    for (int t0 = 0; t0 < T_SEQ; t0 += 256) {
        TILE(t0, 0, 65536, true);
        TILE(t0 + 128, 65536, 0, (t0 + 256 < T_SEQ));
    }
#undef TILE

    // ---- merge 4 kv-splits ----
    float* red_m = reinterpret_cast<float*>(smem + 40960);   // [4][64]
    float* red_l = reinterpret_cast<float*>(smem + 43008);   // [4][64]
    int row64[2]; float fac[2];
#pragma unroll
    for (int qt = 0; qt < 2; ++qt) row64[qt] = qt2 * 32 + qt * 16 + lo;
    if (hi == 0) {
#pragma unroll
        for (int qt = 0; qt < 2; ++qt) {
            red_m[split * 64 + row64[qt]] = m_run[qt];
            red_l[split * 64 + row64[qt]] = l_run[qt];
        }
    }
    __syncthreads();
#pragma unroll
    for (int qt = 0; qt < 2; ++qt) {
        float M = -1e30f;
#pragma unroll
        for (int s = 0; s < 4; ++s) M = fmaxf(M, red_m[s * 64 + row64[qt]]);
        float L = 0.f;
#pragma unroll
        for (int s = 0; s < 4; ++s) L += red_l[s * 64 + row64[qt]] * exp2f(red_m[s * 64 + row64[qt]] - M);
        fac[qt] = exp2f(m_run[qt] - M) / L;
    }
    float* out_lds = reinterpret_cast<float*>(smem);  // [64][132] fp32 = 33792B
    for (int s = 0; s < 4; ++s) {
        if (split == s) {
#pragma unroll
            for (int qt = 0; qt < 2; ++qt)
#pragma unroll
                for (int dt = 0; dt < 8; ++dt)
#pragma unroll
                    for (int r = 0; r < 4; ++r) {
                        int d = dt * 16 + hi * 4 + r;
                        float v = accO[qt][dt][r] * fac[qt];
                        float* p = &out_lds[row64[qt] * 132 + d];
                        if (s == 0) *p = v; else *p += v;
                    }
        }
        __syncthreads();
    }
    {
        int row = tid >> 3, d0 = (tid & 7) * 16;
        float* op = out + ((size_t)b * T_SEQ + q0 + row) * 128 + d0;
#pragma unroll
        for (int j = 0; j < 4; ++j) {
            float4 v;
            v.x = out_lds[row * 132 + d0 + j * 4 + 0];
            v.y = out_lds[row * 132 + d0 + j * 4 + 1];
            v.z = out_lds[row * 132 + d0 + j * 4 + 2];
            v.w = out_lds[row * 132 + d0 + j * 4 + 3];
            *reinterpret_cast<float4*>(op + j * 4) = v;
        }
    }
}

extern "C" void kernel_launch(void* const* d_in, const int* in_sizes, int n_in,
                              void* d_out, int out_size, void* d_ws, size_t ws_size,
                              hipStream_t stream)
{
    (void)in_sizes; (void)n_in; (void)out_size; (void)ws_size;
    const float* x  = (const float*)d_in[0];
    const float* Wq = (const float*)d_in[1];
    const float* bq = (const float*)d_in[2];
    const float* Wk = (const float*)d_in[3];
    const float* bk = (const float*)d_in[4];
    const float* Wv = (const float*)d_in[5];
    const float* bv = (const float*)d_in[6];
    float* out = (float*)d_out;

    _Float16* qf = (_Float16*)d_ws;
    _Float16* kf = qf + (size_t)4 * T_SEQ * D_HEAD;
    _Float16* vt = kf + (size_t)4 * T_SEQ * D_HEAD;

    proj_kernel<<<dim3(256, 3), 256, 0, stream>>>(x, Wq, bq, Wk, bk, Wv, bv, qf, kf, vt);
    attn_kernel<<<dim3(256), 512, 0, stream>>>(qf, kf, vt, out);
}

// Round 7
// 78.407 us; speedup vs baseline: 1.4929x; 1.0878x over previous
//
#include <hip/hip_runtime.h>
#include <cstdint>

typedef _Float16 half2_t __attribute__((ext_vector_type(2)));
typedef _Float16 half4_t __attribute__((ext_vector_type(4)));
typedef _Float16 half8_t __attribute__((ext_vector_type(8)));
typedef float floatx4 __attribute__((ext_vector_type(4)));

#define T_SEQ 4096
#define D_HEAD 128
#define SCALE_LOG2 0.12751742526f  // log2(e)/sqrt(128), folded into q at proj time

__device__ __forceinline__ void gload16(const void* src, void* dst_lds) {
    using gptr_t = const __attribute__((address_space(1))) unsigned int*;
    using lptr_t = __attribute__((address_space(3))) unsigned int*;
    __builtin_amdgcn_global_load_lds((gptr_t)(uintptr_t)src,
                                     (lptr_t)(unsigned int)(uintptr_t)dst_lds, 16, 0, 0);
}

__device__ __forceinline__ float exp2_raw(float x) {
#if __has_builtin(__builtin_amdgcn_exp2f)
    return __builtin_amdgcn_exp2f(x);   // raw v_exp_f32, no fixup code
#else
    return exp2f(x);
#endif
}

// ---------------- QKV projection (MFMA f16, fp32 accumulate) ----------------
__global__ __launch_bounds__(256) void proj_kernel(
    const float* __restrict__ x,
    const float* __restrict__ Wq, const float* __restrict__ bq,
    const float* __restrict__ Wk, const float* __restrict__ bk,
    const float* __restrict__ Wv, const float* __restrict__ bv,
    _Float16* __restrict__ qf, _Float16* __restrict__ kf, _Float16* __restrict__ vt)
{
    __shared__ __align__(16) _Float16 Ws[128 * 136];
    __shared__ __align__(16) _Float16 xs[64 * 136];

    const int t = threadIdx.x;
    const int mat = blockIdx.y;
    const float* W = (mat == 0) ? Wq : (mat == 1) ? Wk : Wv;
    const float* bias = (mat == 0) ? bq : (mat == 1) ? bk : bv;
    const float osc = (mat == 0) ? SCALE_LOG2 : 1.0f;
    const int r0 = blockIdx.x * 64;

    {
        const int o = t >> 1;
        const int i0 = (t & 1) * 64;
        for (int jj = 0; jj < 8; ++jj) {
            floatx4 w0 = *reinterpret_cast<const floatx4*>(W + o * 128 + i0 + jj * 8);
            floatx4 w1 = *reinterpret_cast<const floatx4*>(W + o * 128 + i0 + jj * 8 + 4);
            half8_t h;
            h[0]=(_Float16)w0[0]; h[1]=(_Float16)w0[1]; h[2]=(_Float16)w0[2]; h[3]=(_Float16)w0[3];
            h[4]=(_Float16)w1[0]; h[5]=(_Float16)w1[1]; h[6]=(_Float16)w1[2]; h[7]=(_Float16)w1[3];
            *reinterpret_cast<half8_t*>(&Ws[o * 136 + i0 + jj * 8]) = h;
        }
    }
    {
        const int row = t >> 2;
        const int c0 = (t & 3) * 32;
        for (int jj = 0; jj < 4; ++jj) {
            floatx4 w0 = *reinterpret_cast<const floatx4*>(x + (size_t)(r0 + row) * 128 + c0 + jj * 8);
            floatx4 w1 = *reinterpret_cast<const floatx4*>(x + (size_t)(r0 + row) * 128 + c0 + jj * 8 + 4);
            half8_t h;
            h[0]=(_Float16)w0[0]; h[1]=(_Float16)w0[1]; h[2]=(_Float16)w0[2]; h[3]=(_Float16)w0[3];
            h[4]=(_Float16)w1[0]; h[5]=(_Float16)w1[1]; h[6]=(_Float16)w1[2]; h[7]=(_Float16)w1[3];
            *reinterpret_cast<half8_t*>(&xs[row * 136 + c0 + jj * 8]) = h;
        }
    }
    __syncthreads();

    const int w = t >> 6;
    const int lane = t & 63;
    const int lo = lane & 15, hi = lane >> 4;

    floatx4 acc[8] = {};
    for (int dc = 0; dc < 4; ++dc) {
        half8_t a8 = *reinterpret_cast<const half8_t*>(&xs[(w * 16 + lo) * 136 + dc * 32 + hi * 8]);
        for (int ot = 0; ot < 8; ++ot) {
            half8_t b8 = *reinterpret_cast<const half8_t*>(&Ws[(ot * 16 + lo) * 136 + dc * 32 + hi * 8]);
            acc[ot] = __builtin_amdgcn_mfma_f32_16x16x32_f16(a8, b8, acc[ot], 0, 0, 0);
        }
    }
    __syncthreads();

    float bb[8];
    for (int ot = 0; ot < 8; ++ot) bb[ot] = bias[ot * 16 + lo];

    if (mat < 2) {
        _Float16* ol = xs;
        for (int ot = 0; ot < 8; ++ot)
            for (int r = 0; r < 4; ++r)
                ol[(w * 16 + hi * 4 + r) * 136 + ot * 16 + lo] = (_Float16)((acc[ot][r] + bb[ot]) * osc);
        __syncthreads();
        _Float16* dst = (mat == 0) ? qf : kf;
        for (int i = 0; i < 4; ++i) {
            int c = t + 256 * i;
            int row = c >> 4, p = c & 15;
            half8_t v = *reinterpret_cast<const half8_t*>(&ol[row * 136 + p * 8]);
            *reinterpret_cast<half8_t*>(dst + (size_t)(r0 + row) * 128 + p * 8) = v;
        }
    } else {
        _Float16* vl = Ws;  // [128][72]
        for (int ot = 0; ot < 8; ++ot)
            for (int r = 0; r < 4; ++r)
                vl[(ot * 16 + lo) * 72 + w * 16 + hi * 4 + r] = (_Float16)(acc[ot][r] + bb[ot]);
        __syncthreads();
        const int b = r0 >> 12, tl0 = r0 & 4095;
        for (int i = 0; i < 4; ++i) {
            int c = t + 256 * i;
            int d = c >> 3, p = c & 7;
            half8_t v = *reinterpret_cast<const half8_t*>(&vl[d * 72 + p * 8]);
            *reinterpret_cast<half8_t*>(vt + ((size_t)(b * 128 + d)) * 4096 + tl0 + p * 8) = v;
        }
    }
}

// ---------------- flash attention ----------------
// 256 blocks x 512 threads = 8 waves: 2 q-groups (32 q as 2x16) x 4 kv-splits (16 kv).
// kv tile = 64, TRIPLE-buffered (3 x 32KB). Pipeline per iteration t:
//   stage(t+1)->NXT | QK(t) from CUR | rescale-check | PV(t-1) from PRV | sm-finish(t) | Vwrite(NXT) | bar
// Softmax steady-state has NO cross-lane ops (lane-local defer-max + partial l_run).
__global__ __launch_bounds__(512, 1) void attn_kernel(
    const _Float16* __restrict__ qf, const _Float16* __restrict__ kf,
    const _Float16* __restrict__ vt, float* __restrict__ out)
{
    __shared__ __align__(16) char smem[100352];   // 3x32KB buffers + red arrays

    const int tid = threadIdx.x;
    const int w = tid >> 6, lane = tid & 63;
    const int lo = lane & 15, hi = lane >> 4;
    const int qg = w & 1, ksp = w >> 1;   // 2 q-groups x 4 kv-splits (16 kv each)

    // XCD-aware swizzle
    const int bx = blockIdx.x;
    const int wg = (bx & 7) * 32 + (bx >> 3);
    const int b = wg >> 6;
    const int q0 = (wg & 63) * 64;

    const char* kbc = (const char*)(kf + (size_t)b * T_SEQ * 128);
    const char* vbc = (const char*)(vt + (size_t)b * 128 * T_SEQ);

    // K staging: 2 gload16/thread. LDS[row][slot] = K[row][slot ^ (row&7)], rows 256B.
    int koff[2], kdst[2];
#pragma unroll
    for (int r = 0; r < 2; ++r) {
        int seg = w * 2 + r;
        int slot = lane & 15;
        int row = seg * 4 + (lane >> 4);
        koff[r] = row * 256 + ((slot ^ (row & 7)) << 4);
        kdst[r] = seg * 1024 + lane * 16;
    }
    // V staging (reg->LDS, one b128 write per unit): V rows [d][64kv]=128B=8 units,
    // unit u holds kv chunk u ^ (d&7).
    int vgo[2], vwl[2];
#pragma unroll
    for (int i = 0; i < 2; ++i) {
        int d = (tid >> 3) + 64 * i;
        vgo[i] = d * (T_SEQ * 2) + (tid & 7) * 16;
        vwl[i] = 16384 + d * 128 + (((tid & 7) ^ (d & 7)) << 4);
    }
    // LDS read offsets (loop-invariant)
    int kro[4];
#pragma unroll
    for (int dc = 0; dc < 4; ++dc)
        kro[dc] = (ksp * 16 + lo) * 256 + (((dc * 4 + hi) ^ (lo & 7)) << 4);
    int vro[8];
#pragma unroll
    for (int dt = 0; dt < 8; ++dt)
        vro[dt] = 16384 + (dt * 16 + lo) * 128 +
                  (((ksp * 2 + (hi >> 1)) ^ (lo & 7)) << 4) + ((hi & 1) << 3);

    // Q fragments (pre-scaled by log2(e)/sqrt(D)): d-enum dc*32+hi*8+j, matches K-side
    half8_t qfA[4], qfB[4];
    {
        const _Float16* qa = qf + ((size_t)b * T_SEQ + q0 + qg * 32 + lo) * 128;
        const _Float16* qb = qa + 16 * 128;
#pragma unroll
        for (int dc = 0; dc < 4; ++dc) {
            qfA[dc] = *reinterpret_cast<const half8_t*>(qa + dc * 32 + hi * 8);
            qfB[dc] = *reinterpret_cast<const half8_t*>(qb + dc * 32 + hi * 8);
        }
    }

    floatx4 accA[8] = {}, accB[8] = {};
    float mA = -1e30f, mB = -1e30f, lA = 0.f, lB = 0.f;   // l is LANE-PARTIAL
    half4_t paA = {}, paB = {};                           // P of previous tile

    // prologue: stage tile 0 into buf0
    gload16(kbc + koff[0], smem + kdst[0]);
    gload16(kbc + koff[1], smem + kdst[1]);
    {
        uint4 v0 = *reinterpret_cast<const uint4*>(vbc + vgo[0]);
        uint4 v1 = *reinterpret_cast<const uint4*>(vbc + vgo[1]);
        *reinterpret_cast<uint4*>(smem + vwl[0]) = v0;
        *reinterpret_cast<uint4*>(smem + vwl[1]) = v1;
    }
    __syncthreads();

#define TILE(T0, CUR, NXT, PRV, PF, DOPREV) do {                                       \
    uint4 vr0, vr1;                                                                    \
    if (PF) {                                                                          \
        const char* vs = vbc + (size_t)((T0) + 64) * 2;                                \
        vr0 = *reinterpret_cast<const uint4*>(vs + vgo[0]);                            \
        vr1 = *reinterpret_cast<const uint4*>(vs + vgo[1]);                            \
        const char* ks = kbc + (size_t)((T0) + 64) * 256;                              \
        gload16(ks + koff[0], smem + (NXT) + kdst[0]);                                 \
        gload16(ks + koff[1], smem + (NXT) + kdst[1]);                                 \
    }                                                                                  \
    floatx4 sA = {0.f,0.f,0.f,0.f}, sB = {0.f,0.f,0.f,0.f};                            \
    __builtin_amdgcn_s_setprio(1);                                                     \
    _Pragma("unroll")                                                                  \
    for (int dc = 0; dc < 4; ++dc) {                                                   \
        half8_t kf8 = *reinterpret_cast<const half8_t*>(smem + (CUR) + kro[dc]);       \
        sA = __builtin_amdgcn_mfma_f32_16x16x32_f16(kf8, qfA[dc], sA, 0, 0, 0);        \
        sB = __builtin_amdgcn_mfma_f32_16x16x32_f16(kf8, qfB[dc], sB, 0, 0, 0);        \
    }                                                                                  \
    __builtin_amdgcn_s_setprio(0);                                                     \
    float mpA = fmaxf(fmaxf(sA[0], sA[1]), fmaxf(sA[2], sA[3]));                       \
    float mpB = fmaxf(fmaxf(sB[0], sB[1]), fmaxf(sB[2], sB[3]));                       \
    bool ok = (mpA <= mA + 4.0f) && (mpB <= mB + 4.0f);                                \
    if (!__all(ok)) {                                                                  \
        float ra = mpA, rb = mpB;                                                      \
        ra = fmaxf(ra, __shfl_xor(ra, 16)); ra = fmaxf(ra, __shfl_xor(ra, 32));        \
        rb = fmaxf(rb, __shfl_xor(rb, 16)); rb = fmaxf(rb, __shfl_xor(rb, 32));        \
        float nA = fmaxf(mA, ra), nB = fmaxf(mB, rb);                                  \
        float aA = exp2_raw(mA - nA), aB = exp2_raw(mB - nB);                          \
        lA *= aA; lB *= aB;                                                            \
        _Pragma("unroll")                                                              \
        for (int dt = 0; dt < 8; ++dt) { accA[dt] *= aA; accB[dt] *= aB; }             \
        mA = nA; mB = nB;                                                              \
    }                                                                                  \
    if (DOPREV) {                                                                      \
        __builtin_amdgcn_s_setprio(1);                                                 \
        _Pragma("unroll")                                                              \
        for (int dt = 0; dt < 8; ++dt) {                                               \
            half4_t vfr = *reinterpret_cast<const half4_t*>(smem + (PRV) + vro[dt]);   \
            accA[dt] = __builtin_amdgcn_mfma_f32_16x16x16f16(vfr, paA, accA[dt], 0, 0, 0); \
            accB[dt] = __builtin_amdgcn_mfma_f32_16x16x16f16(vfr, paB, accB[dt], 0, 0, 0); \
        }                                                                              \
        __builtin_amdgcn_s_setprio(0);                                                 \
    }                                                                                  \
    {                                                                                  \
        float p0 = exp2_raw(sA[0] - mA), p1 = exp2_raw(sA[1] - mA);                    \
        float p2 = exp2_raw(sA[2] - mA), p3 = exp2_raw(sA[3] - mA);                    \
        lA += (p0 + p1) + (p2 + p3);                                                   \
        half2_t h0 = __builtin_bit_cast(half2_t, __builtin_amdgcn_cvt_pkrtz(p0, p1));  \
        half2_t h1 = __builtin_bit_cast(half2_t, __builtin_amdgcn_cvt_pkrtz(p2, p3));  \
        paA[0] = h0[0]; paA[1] = h0[1]; paA[2] = h1[0]; paA[3] = h1[1];                \
        p0 = exp2_raw(sB[0] - mB); p1 = exp2_raw(sB[1] - mB);                          \
        p2 = exp2_raw(sB[2] - mB); p3 = exp2_raw(sB[3] - mB);                          \
        lB += (p0 + p1) + (p2 + p3);                                                   \
        h0 = __builtin_bit_cast(half2_t, __builtin_amdgcn_cvt_pkrtz(p0, p1));          \
        h1 = __builtin_bit_cast(half2_t, __builtin_amdgcn_cvt_pkrtz(p2, p3));          \
        paB[0] = h0[0]; paB[1] = h0[1]; paB[2] = h1[0]; paB[3] = h1[1];                \
    }                                                                                  \
    if (PF) {                                                                          \
        *reinterpret_cast<uint4*>(smem + (NXT) + vwl[0]) = vr0;                        \
        *reinterpret_cast<uint4*>(smem + (NXT) + vwl[1]) = vr1;                        \
    }                                                                                  \
    __syncthreads();                                                                   \
} while (0)

    // 64 tiles of 64 kv; buffers rotate 0 -> 32768 -> 65536
    TILE(0, 0, 32768, 65536, 1, 0);
    for (int t0 = 1; t0 < 61; t0 += 3) {
        TILE(t0 * 64,       32768, 65536, 0,     1, 1);
        TILE(t0 * 64 + 64,  65536, 0,     32768, 1, 1);
        TILE(t0 * 64 + 128, 0,     32768, 65536, 1, 1);
    }
    TILE(61 * 64, 32768, 65536, 0,     1, 1);
    TILE(62 * 64, 65536, 0,     32768, 1, 1);
    TILE(63 * 64, 0,     32768, 65536, 0, 1);
#undef TILE

    // epilogue: PV of last tile (data in buf0)
#pragma unroll
    for (int dt = 0; dt < 8; ++dt) {
        half4_t vfr = *reinterpret_cast<const half4_t*>(smem + 0 + vro[dt]);
        accA[dt] = __builtin_amdgcn_mfma_f32_16x16x16f16(vfr, paA, accA[dt], 0, 0, 0);
        accB[dt] = __builtin_amdgcn_mfma_f32_16x16x16f16(vfr, paB, accB[dt], 0, 0, 0);
    }

    // ---- reduce lane-partial l across hi-groups (once) ----
    lA += __shfl_xor(lA, 16); lA += __shfl_xor(lA, 32);
    lB += __shfl_xor(lB, 16); lB += __shfl_xor(lB, 32);

    // ---- merge 4 kv-splits ----
    float* red_m = reinterpret_cast<float*>(smem + 98304);   // [4][64]
    float* red_l = reinterpret_cast<float*>(smem + 99328);   // [4][64]
    const int rowA = qg * 32 + lo, rowB = qg * 32 + 16 + lo;
    if (hi == 0) {
        red_m[ksp * 64 + rowA] = mA; red_l[ksp * 64 + rowA] = lA;
        red_m[ksp * 64 + rowB] = mB; red_l[ksp * 64 + rowB] = lB;
    }
    __syncthreads();
    float facA, facB;
    {
        float M = -1e30f, L = 0.f;
#pragma unroll
        for (int s = 0; s < 4; ++s) M = fmaxf(M, red_m[s * 64 + rowA]);
#pragma unroll
        for (int s = 0; s < 4; ++s) L += red_l[s * 64 + rowA] * exp2_raw(red_m[s * 64 + rowA] - M);
        facA = exp2_raw(mA - M) / L;
        M = -1e30f; L = 0.f;
#pragma unroll
        for (int s = 0; s < 4; ++s) M = fmaxf(M, red_m[s * 64 + rowB]);
#pragma unroll
        for (int s = 0; s < 4; ++s) L += red_l[s * 64 + rowB] * exp2_raw(red_m[s * 64 + rowB] - M);
        facB = exp2_raw(mB - M) / L;
    }
    float* out_lds = reinterpret_cast<float*>(smem);  // [64][132] fp32 = 33792B
    for (int s = 0; s < 4; ++s) {
        if (ksp == s) {
#pragma unroll
            for (int dt = 0; dt < 8; ++dt)
#pragma unroll
                for (int r = 0; r < 4; ++r) {
                    int d = dt * 16 + hi * 4 + r;
                    float vA = accA[dt][r] * facA;
                    float vB = accB[dt][r] * facB;
                    float* pA = &out_lds[rowA * 132 + d];
                    float* pB = &out_lds[rowB * 132 + d];
                    if (s == 0) { *pA = vA; *pB = vB; }
                    else        { *pA += vA; *pB += vB; }
                }
        }
        __syncthreads();
    }
    {
        int row = tid >> 3, d0 = (tid & 7) * 16;
        float* op = out + ((size_t)b * T_SEQ + q0 + row) * 128 + d0;
#pragma unroll
        for (int j = 0; j < 4; ++j) {
            float4 v;
            v.x = out_lds[row * 132 + d0 + j * 4 + 0];
            v.y = out_lds[row * 132 + d0 + j * 4 + 1];
            v.z = out_lds[row * 132 + d0 + j * 4 + 2];
            v.w = out_lds[row * 132 + d0 + j * 4 + 3];
            *reinterpret_cast<float4*>(op + j * 4) = v;
        }
    }
}

extern "C" void kernel_launch(void* const* d_in, const int* in_sizes, int n_in,
                              void* d_out, int out_size, void* d_ws, size_t ws_size,
                              hipStream_t stream)
{
    (void)in_sizes; (void)n_in; (void)out_size; (void)ws_size;
    const float* x  = (const float*)d_in[0];
    const float* Wq = (const float*)d_in[1];
    const float* bq = (const float*)d_in[2];
    const float* Wk = (const float*)d_in[3];
    const float* bk = (const float*)d_in[4];
    const float* Wv = (const float*)d_in[5];
    const float* bv = (const float*)d_in[6];
    float* out = (float*)d_out;

    _Float16* qf = (_Float16*)d_ws;
    _Float16* kf = qf + (size_t)4 * T_SEQ * D_HEAD;
    _Float16* vt = kf + (size_t)4 * T_SEQ * D_HEAD;

    proj_kernel<<<dim3(256, 3), 256, 0, stream>>>(x, Wq, bq, Wk, bk, Wv, bv, qf, kf, vt);
    attn_kernel<<<dim3(256), 512, 0, stream>>>(qf, kf, vt, out);
}